// Round 9
// baseline (104.758 us; speedup 1.0000x reference)
//
#include <hip/hip_runtime.h>
#include <hip/hip_bf16.h>
#include <stdint.h>

// STFT power spectrogram as INT8 MFMA GEMM (mfma_i32_32x32x32_i8, exact i32
// accum), 8-barrier-per-K-tile phase rhythm (m201 style, NO asm lgkm pins:
// compiler inserts counted lgkm waits for its own ds_reads).
// C[M=1024][N=59904] = A[1024][1024] x frames[1024][59904], S = (acc*DEQ)^2.
// A rows interleaved: row 2f = win*cos(w_f n), row 2f+1 = -win*sin(w_f n),
// quantized *127. x quantized at scale 127/6.5. Nyquist f=512 via GEMV.

#define NFFT     1024
#define NFREQ    513
#define BATCH    32
#define SAMPLES  480000
#define HOP      256
#define NFRAMES  1872
#define NCOLS    (BATCH * NFRAMES)     // 59904 = 234*256
#define BM       256
#define BN       256
#define BK       64
#define MBLKS    4                     // M = 1024 exactly
#define NBLKS    (NCOLS / BN)          // 234
#define KTILES   16                    // 1024/64
#define NWG      (MBLKS * NBLKS)       // 936 = 8 * 117

#define XQ_BYTES  ((size_t)BATCH * SAMPLES)              // 15,360,000
#define AWS_BYTES ((size_t)MBLKS * KTILES * 1024 * 16)   // 1,048,576

#define XMAX   6.5f
#define SCALE_X (127.0f / XMAX)
#define DEQ    (XMAX / 16129.0f)       // 1/(127*SCALE_X)
#define DEQ2   (DEQ * DEQ)

typedef __attribute__((ext_vector_type(4)))  int i32x4;
typedef __attribute__((ext_vector_type(16))) int i32x16;

// ---------------- prep 1: x f32 -> i8 (scale, clamp, RNE) ----------------
__global__ __launch_bounds__(256) void k_quant_x(const float* __restrict__ x,
                                                 signed char* __restrict__ xq) {
  size_t i = (size_t)blockIdx.x * 256 + threadIdx.x;   // 16 elems per thread
  const float4* x4 = (const float4*)x;
  union { signed char c[16]; uint4 v; } p;
  #pragma unroll
  for (int j = 0; j < 4; ++j) {
    float4 a = x4[i * 4 + j];
    float f[4] = {a.x, a.y, a.z, a.w};
    #pragma unroll
    for (int e = 0; e < 4; ++e) {
      float v = fminf(127.f, fmaxf(-127.f, f[e] * SCALE_X));
      p.c[j * 4 + e] = (signed char)__float2int_rn(v);
    }
  }
  ((uint4*)xq)[i] = p.v;
}

// ---------------- prep 2: DFT matrix i8, tiled + bank-swizzle baked in ----
// E = ((((mblk*16 + kt)*256 + r)*4 + s)*16 + e ; stores A[m=mblk*256+r][k]
// with k = kt*64 + (s ^ ((r>>1)&3))*16 + e   (granule swizzle, see READ_A)
__global__ __launch_bounds__(256) void k_build_A(const float* __restrict__ narr,
                                                 const float* __restrict__ w,
                                                 const float* __restrict__ window,
                                                 signed char* __restrict__ Aws) {
  uint32_t E = blockIdx.x * 256 + threadIdx.x;
  uint32_t e    = E & 15;
  uint32_t s    = (E >> 4) & 3;
  uint32_t r    = (E >> 6) & 255;
  uint32_t kt   = (E >> 14) & 15;
  uint32_t mblk = E >> 18;
  uint32_t m = mblk * 256 + r;
  uint32_t k = kt * 64 + ((s ^ ((r >> 1) & 3)) << 4) + e;
  float ang = w[m >> 1] * narr[k];
  float sn, cs;
  sincosf(ang, &sn, &cs);
  float val = 127.f * window[k] * ((m & 1) ? -sn : cs);
  Aws[E] = (signed char)__float2int_rn(val);
}

// ---------------- Nyquist bin f=512 ----------------
__global__ __launch_bounds__(256) void k_nyq(const signed char* __restrict__ xq,
                                             const float* __restrict__ window,
                                             float* __restrict__ out) {
  const int tid  = threadIdx.x;
  const int lane = tid & 63;
  const int wv   = tid >> 6;
  float wk[16];
  #pragma unroll
  for (int j4 = 0; j4 < 4; ++j4) {
    float4 wv4 = *(const float4*)&window[lane * 16 + j4 * 4];
    const float sc = XMAX / 127.f;
    wk[j4 * 4 + 0] =  wv4.x * sc;
    wk[j4 * 4 + 1] = -wv4.y * sc;
    wk[j4 * 4 + 2] =  wv4.z * sc;
    wk[j4 * 4 + 3] = -wv4.w * sc;
  }
  #pragma unroll
  for (int fi = 0; fi < 4; ++fi) {
    int g = blockIdx.x * 16 + wv * 4 + fi;
    int b = g / NFRAMES;
    int t = g - b * NFRAMES;
    union { int4 v; signed char c[16]; } u;
    u.v = *(const int4*)(xq + (size_t)b * SAMPLES + (size_t)t * HOP + lane * 16);
    float s = 0.f;
    #pragma unroll
    for (int j = 0; j < 16; ++j) s += wk[j] * (float)u.c[j];
    #pragma unroll
    for (int d = 32; d >= 1; d >>= 1) s += __shfl_xor(s, d, 64);
    if (lane == 0)
      out[(size_t)b * (NFREQ * NFRAMES) + (size_t)512 * NFRAMES + t] = s * s;
  }
}

// ---------------- main GEMM ----------------
#define GL2LDS(g, l) __builtin_amdgcn_global_load_lds( \
    (const __attribute__((address_space(1))) uint32_t*)(g), \
    (__attribute__((address_space(3))) uint32_t*)(l), 16, 0, 0)

#define WAITV2_BAR() asm volatile("s_waitcnt vmcnt(2)\ns_barrier" ::: "memory")
#define WAIT0_BAR()  asm volatile("s_waitcnt vmcnt(0)\ns_barrier" ::: "memory")
#define BAR()        asm volatile("s_barrier" ::: "memory")

// LDS bytes: A-par0 @0 (16K), B-par0 @16384, A-par1 @32768, B-par1 @49152.
// Region layout: byte = (row*4 + slot)*16 + e ; slot = k-chunk ^ ((row>>1)&3).

#define STAGE_A(kt, h) do { const int P_ = (kt) & 1; int ci_ = (h) * 512 + tid; \
  GL2LDS(Aws + (((size_t)mblk * KTILES + (kt)) * 1024 + ci_) * 16,              \
         &lds[P_ * 32768 + ci_ * 16]); } while (0)

#define STAGE_B(kt, h) do { const int P_ = (kt) & 1; int ci_ = (h) * 512 + tid; \
  GL2LDS(xq + bsrc[h] + (kt) * 64,                                              \
         &lds[16384 + P_ * 32768 + ci_ * 16]); } while (0)

#define READ_A(qm, P)                                                           \
  _Pragma("unroll") for (int mt_ = 0; mt_ < 2; ++mt_)                           \
  _Pragma("unroll") for (int ks_ = 0; ks_ < 2; ++ks_) {                         \
    int r_ = wr * 128 + (qm) * 64 + mt_ * 32 + lr;                              \
    int sl_ = (ks_ * 2 + hi) ^ ((r_ >> 1) & 3);                                 \
    a[qm][mt_][ks_] = *(const i32x4*)&lds[(P) * 32768 + (r_ * 4 + sl_) * 16];   \
  }

#define READ_B(qn, P)                                                           \
  _Pragma("unroll") for (int ks_ = 0; ks_ < 2; ++ks_) {                         \
    int c_ = wc * 64 + (qn) * 32 + lr;                                          \
    int sl_ = (ks_ * 2 + hi) ^ ((c_ >> 1) & 3);                                 \
    bfr[qn][ks_] = *(const i32x4*)&lds[16384 + (P) * 32768 + (c_ * 4 + sl_) * 16]; \
  }

#define MFMA4(qm, qn) do {                                                      \
  __builtin_amdgcn_s_setprio(1);                                                \
  _Pragma("unroll") for (int ks_ = 0; ks_ < 2; ++ks_)                           \
  _Pragma("unroll") for (int mt_ = 0; mt_ < 2; ++mt_)                           \
    acc[(qm) * 2 + mt_][qn] = __builtin_amdgcn_mfma_i32_32x32x32_i8(            \
        a[qm][mt_][ks_], bfr[qn][ks_], acc[(qm) * 2 + mt_][qn], 0, 0, 0);       \
  __builtin_amdgcn_s_setprio(0);                                                \
  } while (0)

__global__ __launch_bounds__(512, 2) void k_stft(const signed char* __restrict__ xq,
                                                 const signed char* __restrict__ Aws,
                                                 float* __restrict__ out) {
  __shared__ signed char lds[65536];   // 64 KB -> 2 blocks/CU
  const int tid  = threadIdx.x;
  const int lane = tid & 63;
  const int wid  = tid >> 6;
  const int wr = wid >> 2;      // 0..1  (wave rows: 128)
  const int wc = wid & 3;       // 0..3  (wave cols: 64)
  const int lr = lane & 31;     // row/col within 32x32 fragment
  const int hi = lane >> 5;     // k-half selector

  // XCD-bijective block swizzle: 936 = 8*117; mblk fastest -> the 4
  // mblk-siblings (same B-panel) are adjacent on one XCD.
  const int bx = blockIdx.x;
  const int v = (bx & 7) * 117 + (bx >> 3);
  const int nblk = v >> 2;
  const int mblk = v & 3;

  // B staging source addrs (pre-swizzled global source, linear LDS dest).
  size_t bsrc[2];
  #pragma unroll
  for (int h = 0; h < 2; ++h) {
    int col = h * 128 + (tid >> 2);
    int kc = (tid & 3) ^ ((col >> 1) & 3);
    int jcol = nblk * BN + col;
    int b = jcol / NFRAMES;
    int tf = jcol - b * NFRAMES;
    bsrc[h] = (size_t)b * SAMPLES + (size_t)tf * HOP + kc * 16;
  }

  i32x16 acc[4][2];
  #pragma unroll
  for (int i = 0; i < 4; ++i)
    #pragma unroll
    for (int j = 0; j < 2; ++j)
      #pragma unroll
      for (int e = 0; e < 16; ++e) acc[i][j][e] = 0;

  i32x4 a[2][2][2];
  i32x4 bfr[2][2];

  // prologue: A(0) 2, B(0) 2, A(1) 2  -> entering kt0, vmcnt(2) leaves A(1)
  STAGE_A(0, 0); STAGE_A(0, 1);
  STAGE_B(0, 0); STAGE_B(0, 1);
  STAGE_A(1, 0); STAGE_A(1, 1);

  // 8-phase rhythm per K-tile: {reads+stage; BAR; MFMA cluster; BAR} x4.
  // No asm lgkm waits (compiler inserts counted waits for its own ds_reads);
  // counted vmcnt once per kt at entry. Ledger: entering kt, in flight =
  // {A(kt),B(kt),A(kt+1)} = 6 -> vmcnt(2) completes A(kt),B(kt). kt=15:
  // in flight = {A(15),B(15)} = 4 -> vmcnt(0) (B15 must land).
  // WAR: STAGE_A(kt+2) issued post-BAR#4; all parity-P A-reads consumed by
  // MFMA before BAR#4 chip-wide. STAGE_B(kt+1) hits other parity.
  #pragma unroll 2
  for (int kt = 0; kt < KTILES; ++kt) {
    const int P = kt & 1;
    if (kt == KTILES - 1) WAIT0_BAR(); else WAITV2_BAR();
    READ_A(0, P);
    READ_B(0, P);
    if (kt + 1 < KTILES) STAGE_B(kt + 1, 0);
    BAR();
    MFMA4(0, 0);
    BAR();
    READ_A(1, P);
    if (kt + 1 < KTILES) STAGE_B(kt + 1, 1);
    BAR();
    MFMA4(1, 0);
    BAR();
    READ_B(1, P);
    BAR();
    MFMA4(1, 1);
    BAR();
    if (kt + 2 < KTILES) { STAGE_A(kt + 2, 0); STAGE_A(kt + 2, 1); }
    BAR();
    MFMA4(0, 1);
  }

  // epilogue: C/D col = lane&31, row = (reg&3) + 8*(reg>>2) + 4*hi.
  const int colb  = nblk * BN + wc * 64;
  const int fbase = mblk * 128 + wr * 64;
  #pragma unroll
  for (int nt = 0; nt < 2; ++nt) {
    const int col = colb + nt * 32 + lr;
    const int bo = col / NFRAMES;
    const int tf = col - bo * NFRAMES;
    float* op = out + (size_t)bo * (NFREQ * NFRAMES) + tf;
    #pragma unroll
    for (int amt = 0; amt < 4; ++amt) {
      i32x16 vv = acc[amt][nt];
      #pragma unroll
      for (int aa = 0; aa < 4; ++aa) {
        const int f0 = fbase + amt * 16 + aa * 4 + 2 * hi;
        float v0 = (float)vv[aa * 4 + 0], v1 = (float)vv[aa * 4 + 1];
        float v2 = (float)vv[aa * 4 + 2], v3 = (float)vv[aa * 4 + 3];
        op[(size_t)f0 * NFRAMES]       = DEQ2 * (v0 * v0 + v1 * v1);
        op[(size_t)(f0 + 1) * NFRAMES] = DEQ2 * (v2 * v2 + v3 * v3);
      }
    }
  }
}

extern "C" void kernel_launch(void* const* d_in, const int* in_sizes, int n_in,
                              void* d_out, int out_size, void* d_ws, size_t ws_size,
                              hipStream_t stream) {
  const float* x      = (const float*)d_in[0];
  const float* narr   = (const float*)d_in[1];
  const float* w      = (const float*)d_in[2];
  const float* window = (const float*)d_in[3];
  float* out = (float*)d_out;

  signed char* xq  = (signed char*)d_ws;
  signed char* Aws = xq + XQ_BYTES;
  if (ws_size < XQ_BYTES + AWS_BYTES) return;  // 16.4 MB

  k_quant_x<<<(int)(XQ_BYTES / (256 * 16)), 256, 0, stream>>>(x, xq);
  k_build_A<<<(int)(AWS_BYTES / 256), 256, 0, stream>>>(narr, w, window, Aws);
  k_stft<<<NWG, 512, 0, stream>>>(xq, Aws, out);
  k_nyq<<<NCOLS / 16, 256, 0, stream>>>(xq, window, out);
}

// Round 10
// 103.530 us; speedup vs baseline: 1.0119x; 1.0119x over previous
//
#include <hip/hip_runtime.h>
#include <hip/hip_bf16.h>
#include <stdint.h>

// STFT power spectrogram as INT8 MFMA GEMM (mfma_i32_32x32x32_i8, exact i32
// accum), R8 champion schedule + bank-conflict fix (row-bit3 in slot XOR)
// + fused prep kernel (quant / build_A / nyquist in one dispatch).
// C[M=1024][N=59904] = A[1024][1024] x frames[1024][59904], S = (acc*DEQ)^2.
// A rows interleaved: row 2f = win*cos(w_f n), row 2f+1 = -win*sin(w_f n),
// quantized *127. x quantized at scale 127/6.5. Nyquist f=512 from f32 x.

#define NFFT     1024
#define NFREQ    513
#define BATCH    32
#define SAMPLES  480000
#define HOP      256
#define NFRAMES  1872
#define NCOLS    (BATCH * NFRAMES)     // 59904 = 234*256
#define BM       256
#define BN       256
#define BK       64
#define MBLKS    4                     // M = 1024 exactly
#define NBLKS    (NCOLS / BN)          // 234
#define KTILES   16                    // 1024/64
#define NWG      (MBLKS * NBLKS)       // 936 = 8 * 117

#define XQ_BYTES  ((size_t)BATCH * SAMPLES)              // 15,360,000
#define AWS_BYTES ((size_t)MBLKS * KTILES * 1024 * 16)   // 1,048,576

#define XMAX   6.5f
#define SCALE_X (127.0f / XMAX)
#define DEQ    (XMAX / 16129.0f)       // 1/(127*SCALE_X)
#define DEQ2   (DEQ * DEQ)

// fused prep grid layout
#define QX_BLOCKS 3750                 // XQ_BYTES / (256*16)
#define BA_BLOCKS 4096                 // AWS_BYTES / 256
#define NQ_BLOCKS (NCOLS / 16)         // 3744
#define PREP_BLOCKS (QX_BLOCKS + BA_BLOCKS + NQ_BLOCKS)   // 11590

typedef __attribute__((ext_vector_type(4)))  int i32x4;
typedef __attribute__((ext_vector_type(16))) int i32x16;

// slot swizzle: m(row) = ((row>>1)&3) ^ ((row>>3)&1)
// bank audit: granule g = (4*row + slot) mod 8. For 8 consecutive rows
// (lanes): 4 distinct in {c^0..c^3} (even rows) + 4 in {4+c^0..} (odd) = 8
// distinct. Rows 8 apart now DIFFER (bit3 flips slot bit0) -> no collision
// across 16-lane windows (R8's 5.75M-conflict hypothesis).
#define SLOTM(r) ((((r) >> 1) & 3) ^ (((r) >> 3) & 1))

// ---------------- fused prep: quant_x | build_A | nyquist ----------------
__global__ __launch_bounds__(256) void k_prep(const float* __restrict__ x,
                                              const float* __restrict__ narr,
                                              const float* __restrict__ w,
                                              const float* __restrict__ window,
                                              signed char* __restrict__ xq,
                                              signed char* __restrict__ Aws,
                                              float* __restrict__ out) {
  const int bid = blockIdx.x;
  const int tid = threadIdx.x;
  if (bid < QX_BLOCKS) {
    // ---- x f32 -> i8 (scale, clamp, RNE), 16 elems/thread ----
    size_t i = (size_t)bid * 256 + tid;
    const float4* x4 = (const float4*)x;
    union { signed char c[16]; uint4 v; } p;
    #pragma unroll
    for (int j = 0; j < 4; ++j) {
      float4 a = x4[i * 4 + j];
      float f[4] = {a.x, a.y, a.z, a.w};
      #pragma unroll
      for (int e = 0; e < 4; ++e) {
        float v = fminf(127.f, fmaxf(-127.f, f[e] * SCALE_X));
        p.c[j * 4 + e] = (signed char)__float2int_rn(v);
      }
    }
    ((uint4*)xq)[i] = p.v;
  } else if (bid < QX_BLOCKS + BA_BLOCKS) {
    // ---- DFT matrix i8, tiled + bank-swizzle baked in ----
    // E = (((mblk*16 + kt)*256 + r)*4 + s)*16 + e ; stores A[m][k] with
    // k = kt*64 + (s ^ SLOTM(r))*16 + e
    uint32_t E = (uint32_t)(bid - QX_BLOCKS) * 256 + tid;
    uint32_t e    = E & 15;
    uint32_t s    = (E >> 4) & 3;
    uint32_t r    = (E >> 6) & 255;
    uint32_t kt   = (E >> 14) & 15;
    uint32_t mblk = E >> 18;
    uint32_t m = mblk * 256 + r;
    uint32_t k = kt * 64 + ((s ^ SLOTM(r)) << 4) + e;
    float ang = w[m >> 1] * narr[k];
    float sn, cs;
    sincosf(ang, &sn, &cs);
    float val = 127.f * window[k] * ((m & 1) ? -sn : cs);
    Aws[E] = (signed char)__float2int_rn(val);
  } else {
    // ---- Nyquist f=512 from f32 x: S = (sum win[k]*(-1)^k x[t*256+k])^2 ----
    const int lane = tid & 63;
    const int wv   = tid >> 6;
    float wk[16];
    #pragma unroll
    for (int j4 = 0; j4 < 4; ++j4) {
      float4 wv4 = *(const float4*)&window[lane * 16 + j4 * 4];
      wk[j4 * 4 + 0] =  wv4.x;
      wk[j4 * 4 + 1] = -wv4.y;
      wk[j4 * 4 + 2] =  wv4.z;
      wk[j4 * 4 + 3] = -wv4.w;
    }
    #pragma unroll
    for (int fi = 0; fi < 4; ++fi) {
      int g = (bid - QX_BLOCKS - BA_BLOCKS) * 16 + wv * 4 + fi;
      int b = g / NFRAMES;
      int t = g - b * NFRAMES;
      const float* fp = x + (size_t)b * SAMPLES + (size_t)t * HOP + lane * 16;
      float s = 0.f;
      #pragma unroll
      for (int j4 = 0; j4 < 4; ++j4) {
        float4 xv = *(const float4*)(fp + j4 * 4);
        s += wk[j4 * 4 + 0] * xv.x + wk[j4 * 4 + 1] * xv.y +
             wk[j4 * 4 + 2] * xv.z + wk[j4 * 4 + 3] * xv.w;
      }
      #pragma unroll
      for (int d = 32; d >= 1; d >>= 1) s += __shfl_xor(s, d, 64);
      if (lane == 0)
        out[(size_t)b * (NFREQ * NFRAMES) + (size_t)512 * NFRAMES + t] = s * s;
    }
  }
}

// ---------------- main GEMM ----------------
#define GL2LDS(g, l) __builtin_amdgcn_global_load_lds( \
    (const __attribute__((address_space(1))) uint32_t*)(g), \
    (__attribute__((address_space(3))) uint32_t*)(l), 16, 0, 0)

#define WAITV2_BAR() asm volatile("s_waitcnt vmcnt(2)\ns_barrier" ::: "memory")
#define WAIT0_BAR()  asm volatile("s_waitcnt vmcnt(0)\ns_barrier" ::: "memory")
#define BAR()        asm volatile("s_barrier" ::: "memory")

// LDS bytes: A-par0 @0 (16K), B-par0 @16384, A-par1 @32768, B-par1 @49152.
// Region layout: byte = (row*4 + slot)*16 + e ; slot = k-chunk ^ SLOTM(row).

#define STAGE_A(kt, h) do { const int P_ = (kt) & 1; int ci_ = (h) * 512 + tid; \
  GL2LDS(Aws + (((size_t)mblk * KTILES + (kt)) * 1024 + ci_) * 16,              \
         &lds[P_ * 32768 + ci_ * 16]); } while (0)

#define STAGE_B(kt, h) do { const int P_ = (kt) & 1; int ci_ = (h) * 512 + tid; \
  GL2LDS(xq + bsrc[h] + (kt) * 64,                                              \
         &lds[16384 + P_ * 32768 + ci_ * 16]); } while (0)

#define READ_A(qm, P)                                                           \
  _Pragma("unroll") for (int mt_ = 0; mt_ < 2; ++mt_)                           \
  _Pragma("unroll") for (int ks_ = 0; ks_ < 2; ++ks_) {                         \
    int r_ = wr * 128 + (qm) * 64 + mt_ * 32 + lr;                              \
    int sl_ = (ks_ * 2 + hi) ^ SLOTM(r_);                                       \
    a[qm][mt_][ks_] = *(const i32x4*)&lds[(P) * 32768 + (r_ * 4 + sl_) * 16];   \
  }

#define READ_B(qn, P)                                                           \
  _Pragma("unroll") for (int ks_ = 0; ks_ < 2; ++ks_) {                         \
    int c_ = wc * 64 + (qn) * 32 + lr;                                          \
    int sl_ = (ks_ * 2 + hi) ^ SLOTM(c_);                                       \
    bfr[qn][ks_] = *(const i32x4*)&lds[16384 + (P) * 32768 + (c_ * 4 + sl_) * 16]; \
  }

#define MFMA4(qm, qn) do {                                                      \
  __builtin_amdgcn_s_setprio(1);                                                \
  _Pragma("unroll") for (int ks_ = 0; ks_ < 2; ++ks_)                           \
  _Pragma("unroll") for (int mt_ = 0; mt_ < 2; ++mt_)                           \
    acc[(qm) * 2 + mt_][qn] = __builtin_amdgcn_mfma_i32_32x32x32_i8(            \
        a[qm][mt_][ks_], bfr[qn][ks_], acc[(qm) * 2 + mt_][qn], 0, 0, 0);       \
  __builtin_amdgcn_s_setprio(0);                                                \
  } while (0)

__global__ __launch_bounds__(512, 2) void k_stft(const signed char* __restrict__ xq,
                                                 const signed char* __restrict__ Aws,
                                                 float* __restrict__ out) {
  __shared__ signed char lds[65536];   // 64 KB
  const int tid  = threadIdx.x;
  const int lane = tid & 63;
  const int wid  = tid >> 6;
  const int wr = wid >> 2;      // 0..1  (wave rows: 128)
  const int wc = wid & 3;       // 0..3  (wave cols: 64)
  const int lr = lane & 31;     // row/col within 32x32 fragment
  const int hi = lane >> 5;     // k-half selector

  // XCD-bijective block swizzle: 936 = 8*117; mblk fastest -> the 4
  // mblk-siblings (same B-panel) are adjacent on one XCD.
  const int bx = blockIdx.x;
  const int v = (bx & 7) * 117 + (bx >> 3);
  const int nblk = v >> 2;
  const int mblk = v & 3;

  // B staging source addrs (pre-swizzled global source, linear LDS dest).
  // chunk ci = h*512+tid ; col = ci>>2 ; stored slot = ci&3 ;
  // source k-chunk = slot ^ SLOTM(col).
  size_t bsrc[2];
  #pragma unroll
  for (int h = 0; h < 2; ++h) {
    int col = h * 128 + (tid >> 2);
    int kc = (tid & 3) ^ SLOTM(col);
    int jcol = nblk * BN + col;
    int b = jcol / NFRAMES;
    int tf = jcol - b * NFRAMES;
    bsrc[h] = (size_t)b * SAMPLES + (size_t)tf * HOP + kc * 16;
  }

  i32x16 acc[4][2];
  #pragma unroll
  for (int i = 0; i < 4; ++i)
    #pragma unroll
    for (int j = 0; j < 2; ++j)
      #pragma unroll
      for (int e = 0; e < 16; ++e) acc[i][j][e] = 0;

  i32x4 a[2][2][2];
  i32x4 bfr[2][2];

  // prologue: A(0) 2, B(0) 2, A(1) 2  -> entering kt0, vmcnt(2) leaves A(1)
  STAGE_A(0, 0); STAGE_A(0, 1);
  STAGE_B(0, 0); STAGE_B(0, 1);
  STAGE_A(1, 0); STAGE_A(1, 1);

  // R8 rhythm: 4 phases/K-tile, 1 barrier each; counted vmcnt at tile entry.
  // Ledger: entering kt, in flight = {A(kt),B(kt),A(kt+1)}; vmcnt(2)
  // completes A(kt),B(kt). Final tile: vmcnt(0).
  #pragma unroll 2
  for (int kt = 0; kt < KTILES; ++kt) {
    const int P = kt & 1;
    if (kt == KTILES - 1) WAIT0_BAR(); else WAITV2_BAR();
    READ_A(0, P);
    READ_B(0, P);
    if (kt + 1 < KTILES) { STAGE_B(kt + 1, 0); STAGE_B(kt + 1, 1); }
    MFMA4(0, 0);
    BAR();
    READ_A(1, P);
    MFMA4(1, 0);
    BAR();
    READ_B(1, P);
    if (kt + 2 < KTILES) STAGE_A(kt + 2, 0);   // WAR-safe: all READ_A(P) done
    MFMA4(1, 1);
    BAR();
    if (kt + 2 < KTILES) STAGE_A(kt + 2, 1);
    MFMA4(0, 1);
  }

  // epilogue: C/D col = lane&31, row = (reg&3) + 8*(reg>>2) + 4*hi.
  // reg quad (4a..4a+3) = rows (2f0, 2f0+1, 2f0+2, 2f0+3) -> S in-lane.
  const int colb  = nblk * BN + wc * 64;
  const int fbase = mblk * 128 + wr * 64;
  #pragma unroll
  for (int nt = 0; nt < 2; ++nt) {
    const int col = colb + nt * 32 + lr;
    const int bo = col / NFRAMES;
    const int tf = col - bo * NFRAMES;
    float* op = out + (size_t)bo * (NFREQ * NFRAMES) + tf;
    #pragma unroll
    for (int amt = 0; amt < 4; ++amt) {
      i32x16 vv = acc[amt][nt];
      #pragma unroll
      for (int aa = 0; aa < 4; ++aa) {
        const int f0 = fbase + amt * 16 + aa * 4 + 2 * hi;
        float v0 = (float)vv[aa * 4 + 0], v1 = (float)vv[aa * 4 + 1];
        float v2 = (float)vv[aa * 4 + 2], v3 = (float)vv[aa * 4 + 3];
        op[(size_t)f0 * NFRAMES]       = DEQ2 * (v0 * v0 + v1 * v1);
        op[(size_t)(f0 + 1) * NFRAMES] = DEQ2 * (v2 * v2 + v3 * v3);
      }
    }
  }
}

extern "C" void kernel_launch(void* const* d_in, const int* in_sizes, int n_in,
                              void* d_out, int out_size, void* d_ws, size_t ws_size,
                              hipStream_t stream) {
  const float* x      = (const float*)d_in[0];
  const float* narr   = (const float*)d_in[1];
  const float* w      = (const float*)d_in[2];
  const float* window = (const float*)d_in[3];
  float* out = (float*)d_out;

  signed char* xq  = (signed char*)d_ws;
  signed char* Aws = xq + XQ_BYTES;
  if (ws_size < XQ_BYTES + AWS_BYTES) return;  // 16.4 MB

  k_prep<<<PREP_BLOCKS, 256, 0, stream>>>(x, narr, w, window, xq, Aws, out);
  k_stft<<<NWG, 512, 0, stream>>>(xq, Aws, out);
}

// Round 11
// 72.400 us; speedup vs baseline: 1.4469x; 1.4300x over previous
//
#include <hip/hip_runtime.h>
#include <hip/hip_bf16.h>
#include <stdint.h>
#include <math.h>

// STFT power spectrogram via radix-2 decimated INT8 MFMA GEMM.
// X(f) = E(f mod 512) + e^{-i pi f/512} O(f mod 512);  S = |X|^2.
// E/O = 512-pt windowed DFTs of even/odd samples (windows win[2j], win[2j+1]).
// GEMM: M=1024 rows (512 E: f'=0..255 re/im interleaved, 512 O same), K=512.
// Zero rows (imag f'=0) repurposed as real E(256)/O(256) rows -> f=256 and
// f=512 (Nyquist) come free. Combine done in-register in the epilogue.
// mfma_i32_32x32x32_i8 exact i32 accum; R8 schedule rhythm; SLOTM bank swizzle.

#define NFFT     1024
#define NFREQ    513
#define BATCH    32
#define SAMPLES  480000
#define SAMPH    240000                // samples per batch in each half-stream
#define HOPH     128                   // hop in half-stream
#define NFRAMES  1872
#define NCOLS    (BATCH * NFRAMES)     // 59904 = 234*256
#define BN       256
#define MBLKS    4                     // 512 E-rows: 4 x 128; O rides along
#define NBLKS    (NCOLS / BN)          // 234
#define KTILES   16                    // 8 E (K=512) + 8 O (K=512)
#define NWG      (MBLKS * NBLKS)       // 936 = 8 * 117

#define XH_BYTES  ((size_t)BATCH * SAMPLES)                // xe+xo total
#define AWS_BYTES ((size_t)MBLKS * KTILES * 128 * 64)      // 524,288

#define XMAX   6.5f
#define SCALE_X (127.0f / XMAX)
#define DEQ    (XMAX / 16129.0f)
#define DEQ2   (DEQ * DEQ)

// fused prep grid layout
#define QX_BLOCKS 1875                 // 15.36M samples / (256 thr * 32)
#define BA_BLOCKS 2048                 // AWS_BYTES / 256
#define PREP_BLOCKS (QX_BLOCKS + BA_BLOCKS)

typedef __attribute__((ext_vector_type(4)))  int i32x4;
typedef __attribute__((ext_vector_type(16))) int i32x16;

// slot swizzle for 64 B rows (proven 0-conflict in R10)
#define SLOTM(r) ((((r) >> 1) & 3) ^ (((r) >> 3) & 1))

// ---------------- fused prep: quant+deinterleave | build_A ----------------
__global__ __launch_bounds__(256) void k_prep(const float* __restrict__ x,
                                              const float* __restrict__ narr,
                                              const float* __restrict__ w,
                                              const float* __restrict__ window,
                                              signed char* __restrict__ xe,
                                              signed char* __restrict__ xo,
                                              signed char* __restrict__ Aws) {
  const int bid = blockIdx.x;
  const int tid = threadIdx.x;
  if (bid < QX_BLOCKS) {
    // ---- x f32 -> i8, de-interleaved even/odd; 32 samples/thread ----
    size_t i = (size_t)bid * 256 + tid;
    const float4* x4 = (const float4*)x;
    union { signed char c[16]; uint4 v; } pe, po;
    #pragma unroll
    for (int j = 0; j < 8; ++j) {
      float4 a = x4[i * 8 + j];
      float qe = fminf(127.f, fmaxf(-127.f, a.x * SCALE_X));
      float qo = fminf(127.f, fmaxf(-127.f, a.y * SCALE_X));
      float qe2 = fminf(127.f, fmaxf(-127.f, a.z * SCALE_X));
      float qo2 = fminf(127.f, fmaxf(-127.f, a.w * SCALE_X));
      pe.c[j * 2]     = (signed char)__float2int_rn(qe);
      po.c[j * 2]     = (signed char)__float2int_rn(qo);
      pe.c[j * 2 + 1] = (signed char)__float2int_rn(qe2);
      po.c[j * 2 + 1] = (signed char)__float2int_rn(qo2);
    }
    ((uint4*)xe)[i] = pe.v;
    ((uint4*)xo)[i] = po.v;
  } else {
    // ---- A matrix i8 [mblk][kt][r 0..127][slot][16] ----
    // kt<8: E rows (win[2j]), kt>=8: O rows (win[2j+1]).
    // er = mblk*128+r: even -> cos row f'=er/2; odd -> -sin row; er==1 ->
    // repurposed real f'=256 row (cos(pi j)).
    uint32_t E = (uint32_t)(bid - QX_BLOCKS) * 256 + tid;
    uint32_t e    = E & 15;
    uint32_t s    = (E >> 4) & 3;
    uint32_t r    = (E >> 6) & 127;
    uint32_t kt   = (E >> 13) & 15;
    uint32_t mblk = E >> 17;
    uint32_t er = mblk * 128 + r;
    uint32_t j  = (kt & 7) * 64 + ((s ^ SLOTM(r)) << 4) + e;   // 0..511
    uint32_t odd = (kt >> 3) & 1;
    uint32_t widx = (er == 1) ? 512u : (er & ~1u);   // angle = w[widx]*j
    float ang = w[widx] * narr[j];
    float sn, cs;
    sincosf(ang, &sn, &cs);
    float base = ((er & 1) && (er != 1)) ? -sn : cs;
    float val = 127.f * window[2 * j + odd] * base;
    Aws[E] = (signed char)__float2int_rn(val);
  }
}

// ---------------- main GEMM ----------------
#define GL2LDS(g, l) __builtin_amdgcn_global_load_lds( \
    (const __attribute__((address_space(1))) uint32_t*)(g), \
    (__attribute__((address_space(3))) uint32_t*)(l), 16, 0, 0)

#define WAITV1_BAR() asm volatile("s_waitcnt vmcnt(1)\ns_barrier" ::: "memory")
#define WAIT0_BAR()  asm volatile("s_waitcnt vmcnt(0)\ns_barrier" ::: "memory")
#define BAR()        asm volatile("s_barrier" ::: "memory")

// LDS bytes: A @ P*8192 (2x8K), B @ 16384 + P*16384 (2x16K) = 48 KB total.
// Row layout: byte = (row*4 + slot)*16 + e ; slot = k-chunk ^ SLOTM(row).

#define STAGE_A(kt) do { const int P_ = (kt) & 1;                               \
  GL2LDS(Aws + (((size_t)mblk * KTILES + (kt)) * 512 + tid) * 16,               \
         &lds[P_ * 8192 + tid * 16]); } while (0)

#define STAGE_B(kt) do { const int P_ = (kt) & 1;                               \
  const signed char* bb_ = ((kt) < 8) ? xe : xo;                                \
  _Pragma("unroll") for (int h_ = 0; h_ < 2; ++h_) {                            \
    int ci_ = h_ * 512 + tid;                                                   \
    GL2LDS(bb_ + bsrc[h_] + ((kt) & 7) * 64,                                    \
           &lds[16384 + P_ * 16384 + ci_ * 16]); } } while (0)

#define READ_A(P)                                                               \
  _Pragma("unroll") for (int mt_ = 0; mt_ < 2; ++mt_)                           \
  _Pragma("unroll") for (int ks_ = 0; ks_ < 2; ++ks_) {                         \
    int r_ = wr * 64 + mt_ * 32 + lr;                                           \
    int sl_ = (ks_ * 2 + hi) ^ SLOTM(r_);                                       \
    a[mt_][ks_] = *(const i32x4*)&lds[(P) * 8192 + (r_ * 4 + sl_) * 16];        \
  }

#define READ_B(nt, P)                                                           \
  _Pragma("unroll") for (int ks_ = 0; ks_ < 2; ++ks_) {                         \
    int c_ = wc * 64 + (nt) * 32 + lr;                                          \
    int sl_ = (ks_ * 2 + hi) ^ SLOTM(c_);                                       \
    bfr[nt][ks_] = *(const i32x4*)&lds[16384 + (P) * 16384 + (c_ * 4 + sl_) * 16]; \
  }

#define MFMA_CL(ACC, nt) do {                                                   \
  __builtin_amdgcn_s_setprio(1);                                                \
  _Pragma("unroll") for (int ks_ = 0; ks_ < 2; ++ks_)                           \
  _Pragma("unroll") for (int mt_ = 0; mt_ < 2; ++mt_)                           \
    ACC[mt_][nt] = __builtin_amdgcn_mfma_i32_32x32x32_i8(                       \
        a[mt_][ks_], bfr[nt][ks_], ACC[mt_][nt], 0, 0, 0);                      \
  __builtin_amdgcn_s_setprio(0);                                                \
  } while (0)

// per-kt body, R8 rhythm (2 phases, WAR fence between READ_A and STAGE_A)
#define KTBODY(kt, ACC) do {                                                    \
    const int P_k = (kt) & 1;                                                   \
    if ((kt) == KTILES - 1) WAIT0_BAR(); else WAITV1_BAR();                     \
    READ_A(P_k);                                                                \
    READ_B(0, P_k);                                                             \
    if ((kt) + 1 < KTILES) STAGE_B((kt) + 1);                                   \
    MFMA_CL(ACC, 0);                                                            \
    BAR();                                                                      \
    READ_B(1, P_k);                                                             \
    if ((kt) + 2 < KTILES) STAGE_A((kt) + 2);                                   \
    MFMA_CL(ACC, 1);                                                            \
  } while (0)

__global__ __launch_bounds__(512, 2) void k_stft(const signed char* __restrict__ xe,
                                                 const signed char* __restrict__ xo,
                                                 const signed char* __restrict__ Aws,
                                                 float* __restrict__ out) {
  __shared__ signed char lds[49152];   // 48 KB
  const int tid  = threadIdx.x;
  const int lane = tid & 63;
  const int wid  = tid >> 6;
  const int wr = wid >> 2;      // 0..1  (64 A-rows each)
  const int wc = wid & 3;       // 0..3  (64 cols each)
  const int lr = lane & 31;     // row/col within 32x32 fragment
  const int hi = lane >> 5;     // k-half selector

  // XCD-bijective block swizzle: 936 = 8*117; mblk fastest.
  const int bx = blockIdx.x;
  const int v = (bx & 7) * 117 + (bx >> 3);
  const int nblk = v >> 2;
  const int mblk = v & 3;

  // B staging source addrs (pre-swizzled source, linear LDS dest).
  // chunk ci = h*512+tid ; col = ci>>2 ; stored slot = ci&3 ;
  // source k-chunk = slot ^ SLOTM(col). Frame t -> half-stream offset t*128.
  size_t bsrc[2];
  #pragma unroll
  for (int h = 0; h < 2; ++h) {
    int col = h * 128 + (tid >> 2);
    int kc = (tid & 3) ^ SLOTM(col);
    int jcol = nblk * BN + col;
    int b = jcol / NFRAMES;
    int tf = jcol - b * NFRAMES;
    bsrc[h] = (size_t)b * SAMPH + (size_t)tf * HOPH + kc * 16;
  }

  i32x16 accE[2][2], accO[2][2];
  #pragma unroll
  for (int i = 0; i < 2; ++i)
    #pragma unroll
    for (int j = 0; j < 2; ++j)
      #pragma unroll
      for (int e = 0; e < 16; ++e) { accE[i][j][e] = 0; accO[i][j][e] = 0; }

  i32x4 a[2][2];
  i32x4 bfr[2][2];

  // prologue: A(0) 1, B(0) 2, A(1) 1  -> entering kt0: vmcnt(1) leaves A(1)
  STAGE_A(0);
  STAGE_B(0);
  STAGE_A(1);

  // Ledger (3 loads/kt): entering kt, in flight = {A(kt),B(kt)x2,A(kt+1)}=4;
  // vmcnt(1) completes A(kt),B(kt). kt14 exits with {A15,B15x2}=3 -> kt15
  // vmcnt(0). STAGE_A(kt+2) same parity as kt: after the mid BAR (WAR-safe).
  #pragma unroll 2
  for (int kt = 0; kt < 8; ++kt)  KTBODY(kt, accE);
  #pragma unroll 2
  for (int kt = 8; kt < 16; ++kt) KTBODY(kt, accO);

  // ---- epilogue: in-register radix-2 combine ----
  // C/D: col = lane&31, row = (reg&3) + 8*(reg>>2) + 4*hi. Reg quad aa:
  // pair q=0 -> rows (8aa+4hi, +1) = f' = 4aa+2hi ; q=1 -> f'+1.
  // f' = fbase + mt*16 + aa*4 + 2*hi + q, fbase = mblk*64 + wr*32.
  // T(f') = cos(pi f'/512) - i sin(.); P = T*O;
  // S[f'] = DEQ2*|E+P|^2 ; S[512-f'] = DEQ2*|E-P|^2.
  // f'==0 lane: E_im/O_im regs hold E(256)/O(256):
  //   S[0]=(Ere+Ore)^2, S[512]=(Ere-Ore)^2, S[256]=E256^2+O256^2 (x DEQ2).
  const int fbase = mblk * 64 + wr * 32;
  float ctab[16], stab[16];
  #pragma unroll
  for (int mt = 0; mt < 2; ++mt)
    #pragma unroll
    for (int aa = 0; aa < 4; ++aa)
      #pragma unroll
      for (int q = 0; q < 2; ++q) {
        int idx = mt * 8 + aa * 2 + q;
        float fq = (float)(fbase + mt * 16 + aa * 4 + 2 * hi + q);
        sincosf(fq * (float)(M_PI / 512.0), &stab[idx], &ctab[idx]);
      }
  const int colb = nblk * BN + wc * 64;
  #pragma unroll
  for (int nt = 0; nt < 2; ++nt) {
    const int col = colb + nt * 32 + lr;
    const int bo = col / NFRAMES;
    const int tf = col - bo * NFRAMES;
    float* op = out + (size_t)bo * (NFREQ * NFRAMES) + tf;
    #pragma unroll
    for (int mt = 0; mt < 2; ++mt) {
      i32x16 vE = accE[mt][nt];
      i32x16 vO = accO[mt][nt];
      #pragma unroll
      for (int aa = 0; aa < 4; ++aa)
        #pragma unroll
        for (int q = 0; q < 2; ++q) {
          const int fq = fbase + mt * 16 + aa * 4 + 2 * hi + q;
          float Ere = (float)vE[aa * 4 + 2 * q];
          float Eim = (float)vE[aa * 4 + 2 * q + 1];
          float Ore = (float)vO[aa * 4 + 2 * q];
          float Oim = (float)vO[aa * 4 + 2 * q + 1];
          if (fq == 0) {
            float sp = Ere + Ore, sm = Ere - Ore;
            op[0]                          = DEQ2 * sp * sp;
            op[(size_t)512 * NFRAMES]      = DEQ2 * sm * sm;
            op[(size_t)256 * NFRAMES]      = DEQ2 * (Eim * Eim + Oim * Oim);
          } else {
            const int idx = mt * 8 + aa * 2 + q;
            float ct = ctab[idx], st = stab[idx];
            float Pre = ct * Ore + st * Oim;
            float Pim = ct * Oim - st * Ore;
            float ar = Ere + Pre, ai = Eim + Pim;
            float br = Ere - Pre, bi = Eim - Pim;
            op[(size_t)fq * NFRAMES]         = DEQ2 * (ar * ar + ai * ai);
            op[(size_t)(512 - fq) * NFRAMES] = DEQ2 * (br * br + bi * bi);
          }
        }
    }
  }
}

extern "C" void kernel_launch(void* const* d_in, const int* in_sizes, int n_in,
                              void* d_out, int out_size, void* d_ws, size_t ws_size,
                              hipStream_t stream) {
  const float* x      = (const float*)d_in[0];
  const float* narr   = (const float*)d_in[1];
  const float* w      = (const float*)d_in[2];
  const float* window = (const float*)d_in[3];
  float* out = (float*)d_out;

  signed char* xe  = (signed char*)d_ws;                 // BATCH*SAMPH
  signed char* xo  = xe + (size_t)BATCH * SAMPH;
  signed char* Aws = xo + (size_t)BATCH * SAMPH;
  if (ws_size < XH_BYTES + AWS_BYTES) return;  // 15.9 MB

  k_prep<<<PREP_BLOCKS, 256, 0, stream>>>(x, narr, w, window, xe, xo, Aws);
  k_stft<<<NWG, 512, 0, stream>>>(xe, xo, Aws, out);
}